// Round 2
// baseline (684.268 us; speedup 1.0000x reference)
//
#include <hip/hip_runtime.h>
#include <hip/hip_fp16.h>
#include <cstdint>
#include <cstddef>

// x[512,4096] fp32 ; gate/up codes [11008,4096] i32 ; down codes [4096,11008] i32
// absmax blocks of 64 along K ; out [512,4096] fp32
//
// R8 = dequant-once restructure:
//  - Block covers FULL M=512, N-tile 32: 4 waves x (128M x 32N), acc[8][2].
//    Dequant per B element happens exactly ONCE (R7: 4x, R6: 2x) ->
//    DEQB VALU, ptab lookups, and LDS traffic all /4 per output.
//  - B tile 32x64 f16 (4KB) in LDS, stride 80 halfs (16B-aligned rows,
//    bank-clean for b128 reads/writes). ptab back to simple 256 words.
//  - A fragments straight from L2 (no LDS for A): per kt 16 dwordx4/thread.
//    kk0 group issued at kt start, kk1 issued BEFORE the HBM code loads so
//    codes remain newest in the vmcnt queue (R6 aging rule: MFMA waitcnt
//    retires iter-old A frags, leaves HBM codes in flight).
//  - gate/up: 344nt x 2mats = 688 blocks, XCD-chunked swizzle (L2 k-window
//    of xp shared). down: 128nt x 4 K-chunks = 512 blocks, XCD = f(kchunk)
//    so each K-chunk's 2.75MB A-slice stays in one XCD-pair's L2.

using float4v = __attribute__((ext_vector_type(4))) float;
using half8   = __attribute__((ext_vector_type(8))) _Float16;

__constant__ float NF4TAB[16] = {
  -1.0f, -0.6961928009986877f, -0.5250730514526367f, -0.39491748809814453f,
  -0.28444138169288635f, -0.18477343022823334f, -0.09105003625154495f, 0.0f,
  0.07958029955625534f, 0.16093020141124725f, 0.24611230194568634f,
  0.33791524171829224f, 0.44070982933044434f, 0.5626170039176941f,
  0.7229568362236023f, 1.0f };

// barrier that does NOT drain vmcnt: only LDS ordering.
#define BARRIER() asm volatile("s_waitcnt lgkmcnt(0)\n\ts_barrier" ::: "memory")

// Packed A layout (M=512 fixed): element (m,k) at
//   (((k>>5)*32 + (m>>4))*64 + ((k>>3)&3)*16 + (m&15))*8 + (k&7)
// -> frag (mb,kb): 64 lanes x 16B dense at (kb*32+mb)*512 + lane*8.

// C[512 x N] = A_packed * dequant(codes[N x K])^T
// Block 512M x 32N, BK=64, 4 waves, wave tile 128x32 (8x2 MFMA 16x16x32 f16).
// ATOMIC=false: r2 selects gate/up matrix; C stored f16 PACKED.
// ATOMIC=true : r2 = K-chunk (split-K); fp32 atomicAdd into row-major outF.
template <bool ATOMIC>
__global__ __launch_bounds__(256, 3) void gemm_nf4(
    const __half* __restrict__ Apk,
    const int* __restrict__ c0, const float* __restrict__ am0,
    const int* __restrict__ c1, const float* __restrict__ am1,
    __half* __restrict__ o0, __half* __restrict__ o1,
    float* __restrict__ outF,
    int N, int K, int Kc, int Ntiles)
{
  __shared__ __half    Bb[2][32 * 80];   // 10 KB double-buffered B tile (stride 80)
  __shared__ unsigned  ptab[256];        // packed f16 pair {tab[lo],tab[hi]}

  const int tid  = threadIdx.x;
  const int lane = tid & 63;
  const int wave = tid >> 6;
  const int l15  = lane & 15;
  const int hi8  = (lane >> 4) << 3;

  {
    __half2 pr = __floats2half2_rn(NF4TAB[tid & 15], NF4TAB[tid >> 4]);
    ptab[tid] = *(const unsigned*)&pr;
  }

  int nt, r2;
  if (ATOMIC) {
    // XCD = blockIdx%8 (heuristic). Pin each K-chunk to an XCD pair so its
    // A-slice (512 x 2752 f16 = 2.75 MB) lives in that pair's L2.
    const int xcd  = blockIdx.x & 7;
    const int slot = blockIdx.x >> 3;            // 0..63
    r2 = xcd >> 1;                               // K-chunk 0..3
    nt = (xcd & 1) * (Ntiles >> 1) + slot;       // 0..127
  } else {
    const int nwg = gridDim.x;
    const int bid = (blockIdx.x & 7) * (nwg >> 3) + (blockIdx.x >> 3);
    nt = bid % Ntiles;
    r2 = bid / Ntiles;                           // matrix select
  }

  const int k0 = ATOMIC ? r2 * Kc : 0;
  const int nk = Kc >> 6;
  const int* codes  = (!ATOMIC && r2) ? c1 : c0;
  const float* amax = (!ATOMIC && r2) ? am1 : am0;
  __half* outH      = (!ATOMIC && r2) ? o1 : o0;

  const int col0 = nt * 32;
  const int Kb   = K >> 6;

  // code staging: thread -> (row bn = tid>>3, eighth bq = tid&7): 8 codes
  const int bn = tid >> 3;                       // 0..31
  const int bq = tid & 7;                        // 0..7
  const int4* cSrc   = (const int4*)(codes + (size_t)(col0 + bn) * K + k0);
  const float* amSrc = amax + (size_t)(col0 + bn) * Kb + (k0 >> 6);

  // packed-A base: wave owns 128 rows = 8 m-blocks
  const int kb0 = k0 >> 5;
  const int mb0 = wave * 8;
  const __half* pA = Apk + (size_t)mb0 * 512 + (size_t)lane * 8;

  float4v acc[8][2];
  {
    float4v z = {0.f, 0.f, 0.f, 0.f};
    #pragma unroll
    for (int i = 0; i < 8; ++i)
      #pragma unroll
      for (int j = 0; j < 2; ++j) acc[i][j] = z;
  }

  int4  cr[2][2];      // compile-time slot indices everywhere (R4 lesson)
  float amr[2];
  half8 apf[8], apf2[8];

#define LOADC(S, KT)                                                            \
  { const int4* _p = cSrc + (KT) * 16;                                          \
    cr[S][0] = _p[bq * 2]; cr[S][1] = _p[bq * 2 + 1];                           \
    amr[S] = amSrc[KT]; }

#define DEQB(BUFI, S)                                                           \
  { const __half _ah = __float2half(amr[S]);                                    \
    const __half2 _am2 = __half2{_ah, _ah};                                     \
    unsigned _w0 = ptab[cr[S][0].x | (cr[S][0].y << 4)];                        \
    unsigned _w1 = ptab[cr[S][0].z | (cr[S][0].w << 4)];                        \
    unsigned _w2 = ptab[cr[S][1].x | (cr[S][1].y << 4)];                        \
    unsigned _w3 = ptab[cr[S][1].z | (cr[S][1].w << 4)];                        \
    __half2 _p0 = __hmul2(*(const __half2*)&_w0, _am2);                         \
    __half2 _p1 = __hmul2(*(const __half2*)&_w1, _am2);                         \
    __half2 _p2 = __hmul2(*(const __half2*)&_w2, _am2);                         \
    __half2 _p3 = __hmul2(*(const __half2*)&_w3, _am2);                         \
    uint4 _wv;                                                                  \
    _wv.x = *(const unsigned*)&_p0; _wv.y = *(const unsigned*)&_p1;             \
    _wv.z = *(const unsigned*)&_p2; _wv.w = *(const unsigned*)&_p3;             \
    *(uint4*)&Bb[BUFI][bn * 80 + bq * 8] = _wv; }

// 8 A-frags of k-tile KT, half KK, from L2 (imm-offset friendly: i*512 halfs)
#define LOADA(DST, KT, KK)                                                      \
  { const __half* _pa = pA + ((size_t)(kb0 + (KT) * 2 + (KK)) << 14);           \
    _Pragma("unroll")                                                           \
    for (int _i = 0; _i < 8; ++_i)                                              \
      DST[_i] = *(const half8*)(_pa + _i * 512); }

#define LDBF(BF, S, KK)                                                         \
  { _Pragma("unroll")                                                           \
    for (int _j = 0; _j < 2; ++_j)                                              \
      BF[_j] = *(const half8*)&Bb[S][(_j * 16 + l15) * 80 + (KK) * 32 + hi8]; }

#define MFMA16(APF, BF)                                                         \
  { _Pragma("unroll")                                                           \
    for (int _i = 0; _i < 8; ++_i)                                              \
      _Pragma("unroll")                                                         \
      for (int _j = 0; _j < 2; ++_j)                                            \
        acc[_i][_j] = __builtin_amdgcn_mfma_f32_16x16x32_f16(APF[_i], BF[_j], acc[_i][_j], 0, 0, 0); }

  // ---- prologue: codes t=0 -> slot0, t=1 -> slot1 (slot = t&1)
  LOADC(0, 0);
  if (nk > 1) LOADC(1, 1);
  BARRIER();                       // ptab visible
  DEQB(0, 0);
  if (nk > 2) LOADC(0, 2);         // t=2 -> slot0; HBM loads newest
  BARRIER();                       // Bb[0] visible; vmem stays in flight

// Issue order per kt: A kk0 (L2) -> DEQB next tile (waits 2-iter-old codes,
// leaves A in flight) -> A kk1 (L2) -> HBM codes LAST -> bf reads -> MFMA
// kk0 (vmcnt leaves kk1+codes in flight) -> bf kk1 -> MFMA kk1 (leaves
// codes in flight) -> lgkm-only barrier.
#define BODY(KT, S, NP)                                                         \
  { LOADA(apf, KT, 0);                                                          \
    if ((KT) + 1 < nk) DEQB(NP, NP);                                            \
    LOADA(apf2, KT, 1);                                                         \
    if ((KT) + 3 < nk) LOADC(NP, (KT) + 3);                                     \
    half8 bf[2];                                                                \
    LDBF(bf, S, 0);                                                             \
    MFMA16(apf, bf);                                                            \
    LDBF(bf, S, 1);                                                             \
    MFMA16(apf2, bf);                                                           \
    BARRIER(); }

  int kt = 0;
  while (kt + 2 <= nk) { BODY(kt, 0, 1); BODY(kt + 1, 1, 0); kt += 2; }
  if (kt < nk) BODY(kt, 0, 1);     // odd-nk tail (down: nk=43; 42&1==0 OK)

  // ---- epilogue. C/D map: col = lane&15 (n), row = (lane>>4)*4 + reg (m)
  if (ATOMIC) {
    const int ccol0 = col0 + l15;
    const int crow0 = wave * 128 + ((lane >> 4) << 2);
    #pragma unroll
    for (int i = 0; i < 8; ++i)
      #pragma unroll
      for (int j = 0; j < 2; ++j)
        #pragma unroll
        for (int rr = 0; rr < 4; ++rr) {
          const size_t idx = (size_t)(crow0 + i * 16 + rr) * N + (ccol0 + j * 16);
          atomicAdd(&outF[idx], acc[i][j][rr]);
        }
  } else {
    // store C packed (m = token row, n = this GEMM's out col = down's K):
    //   (((n>>5)*32 + (m>>4))*64 + ((n>>3)&3)*16 + (m&15))*8 + (n&7)
    const int jj    = lane & 7;
    const int lb    = (lane >> 3) & 1;
    const int rbase = (lane >> 4) << 2;
    const int kb    = col0 >> 5;               // single 32-col block
    #pragma unroll
    for (int i = 0; i < 8; ++i) {
      const int mb = wave * 8 + i;
      #pragma unroll
      for (int j = 0; j < 2; ++j) {
        const int lp = (j * 2 + lb) * 16 + rbase;
        #pragma unroll
        for (int rr = 0; rr < 4; ++rr) {
          const size_t a = ((size_t)(kb * 32 + mb) * 64 + (lp + rr)) * 8 + jj;
          outH[a] = __float2half(acc[i][j][rr]);
        }
      }
    }
  }
#undef LOADC
#undef DEQB
#undef LOADA
#undef LDBF
#undef MFMA16
#undef BODY
}

// x fp32 row-major [512][4096] -> packed f16 fragment layout.
__global__ void cast_pack_kernel(const float* __restrict__ x,
                                 __half* __restrict__ xp, int nGrp) {
  int pid = blockIdx.x * blockDim.x + threadIdx.x;   // one per 8 halfs
  if (pid >= nGrp) return;
  const int lane = pid & 63;
  const int grp  = pid >> 6;
  const int mb   = grp & 31;          // M=512 -> 32 m-tiles
  const int kb   = grp >> 5;
  const int m = mb * 16 + (lane & 15);
  const int k = kb * 32 + ((lane >> 4) << 3);
  const float4* src = (const float4*)(x + (size_t)m * 4096 + k);
  float4 v0 = src[0], v1 = src[1];
  __half2 h0 = __floats2half2_rn(v0.x, v0.y), h1 = __floats2half2_rn(v0.z, v0.w);
  __half2 h2 = __floats2half2_rn(v1.x, v1.y), h3 = __floats2half2_rn(v1.z, v1.w);
  uint4 o;
  o.x = *(const unsigned*)&h0; o.y = *(const unsigned*)&h1;
  o.z = *(const unsigned*)&h2; o.w = *(const unsigned*)&h3;
  ((uint4*)xp)[pid] = o;
}

// elementwise silu(g)*u — layout-agnostic (g,u share the packed layout).
__global__ void swiglu_kernel(const __half* __restrict__ g,
                              const __half* __restrict__ u,
                              __half* __restrict__ h, int n2) {
  int i = blockIdx.x * blockDim.x + threadIdx.x;
  if (i < n2) {
    float2 gf = __half22float2(((const __half2*)g)[i]);
    float2 uf = __half22float2(((const __half2*)u)[i]);
    float h0 = gf.x / (1.f + __expf(-gf.x)) * uf.x;
    float h1 = gf.y / (1.f + __expf(-gf.y)) * uf.y;
    ((__half2*)h)[i] = __floats2half2_rn(h0, h1);
  }
}

extern "C" void kernel_launch(void* const* d_in, const int* in_sizes, int n_in,
                              void* d_out, int out_size, void* d_ws, size_t ws_size,
                              hipStream_t stream)
{
  (void)in_sizes; (void)n_in; (void)ws_size;
  const float* x            = (const float*)d_in[0];
  const int*   gate_codes   = (const int*)d_in[1];
  const float* gate_absmax  = (const float*)d_in[2];
  const int*   up_codes     = (const int*)d_in[3];
  const float* up_absmax    = (const float*)d_in[4];
  const int*   down_codes   = (const int*)d_in[5];
  const float* down_absmax  = (const float*)d_in[6];
  float* out = (float*)d_out;

  // ws: xp 4MB | g 11.3MB | u 11.3MB   (h = silu(g)*u written in place over g)
  __half* xp = (__half*)d_ws;
  __half* g  = xp + (size_t)512 * 4096;
  __half* u  = g  + (size_t)512 * 11008;

  hipMemsetAsync(d_out, 0, (size_t)out_size * sizeof(float), stream);

  cast_pack_kernel<<<1024, 256, 0, stream>>>(x, xp, (512 * 4096) / 8);

  // fused gate+up: 344 Ntiles x 2 mats = 688 blocks (full M per block)
  gemm_nf4<false><<<688, 256, 0, stream>>>(xp, gate_codes, gate_absmax,
                                           up_codes, up_absmax,
                                           g, u, nullptr,
                                           11008, 4096, 4096, 344);

  swiglu_kernel<<<11008, 256, 0, stream>>>(g, u, g, (512 * 11008) / 2);

  // down: out += h * Wd^T, split-K=4: 128 Ntiles x 4 = 512 blocks
  gemm_nf4<true><<<512, 256, 0, stream>>>(g, down_codes, down_absmax,
                                          nullptr, nullptr, nullptr, nullptr,
                                          out, 4096, 11008, 2752, 128);
}